// Round 11
// baseline (61.797 us; speedup 1.0000x reference)
//
#include <hip/hip_runtime.h>

static constexpr int B_ROWS = 1048576;
static constexpr int T_LEN  = 32;
static constexpr int NTHR   = 256;
static constexpr int NBLK   = 2048;                  // 2 rows/thread
static constexpr int HALF   = B_ROWS / 2;            // row1 = row0 + HALF

typedef float f32x2 __attribute__((ext_vector_type(2)));
typedef float f32x4 __attribute__((ext_vector_type(4)));
typedef f32x4 f32x4_a4 __attribute__((aligned(4)));

// Pack 4 obs floats into 4-bit codes. fminf(NaN, 6) == 6 -> sentinel in 1 op.
__device__ __forceinline__ unsigned pk4(const float4 v) {
    const unsigned o0 = (unsigned)(int)fminf(v.x, 6.0f);
    const unsigned o1 = (unsigned)(int)fminf(v.y, 6.0f);
    const unsigned o2 = (unsigned)(int)fminf(v.z, 6.0f);
    const unsigned o3 = (unsigned)(int)fminf(v.w, 6.0f);
    return o0 | (o1 << 4) | (o2 << 8) | (o3 << 12);
}
#define OC(P, I) ((int)(((P) >> (4 * (I))) & 7u))

// One step for BOTH rows, float2-packed (targets v_pk_fma_f32 dual-issue).
// e0/e2 from per-row LDS tables; e1 via tiny select (codes 4/5/6 only,
// fe15 wave-uniform). Code 6 (dead) = emissions (1,1,1): T rows sum to 1,
// so dead steps preserve sum(alpha) exactly (frozen-alpha semantics).
#define STEPP(OA, OB) {                                                      \
    const int oa = (OA), ob = (OB);                                          \
    const float2 ea = sE[oa][0][tid];                                        \
    const float2 eb = sE[ob][1][tid];                                        \
    f32x2 e0p; e0p.x = ea.x; e0p.y = eb.x;                                   \
    f32x2 e2p; e2p.x = ea.y; e2p.y = eb.y;                                   \
    f32x2 e1p;                                                               \
    e1p.x = (oa==4)?fy3a:(oa==5)?fe15:(oa==6)?1.0f:0.0f;                     \
    e1p.y = (ob==4)?fy3b:(ob==5)?fe15:(ob==6)?1.0f:0.0f;                     \
    const f32x2 n0 = (a0p*t00p + a1p*t10p + a2p*t20p) * e0p;                 \
    const f32x2 n1 = (a0p*t01p + a1p*t11p + a2p*t21p) * e1p;                 \
    const f32x2 n2 = (a0p*t02p + a1p*t12p + a2p*t22p) * e2p;                 \
    a0p = n0; a1p = n1; a2p = n2;                                            \
}

// Power-of-2 rescale every 2 steps; self-limits after row death (sum
// preserved), exactly compensated by kk.
#define RESCALEP {                                                           \
    const float sa = a0p.x + a1p.x + a2p.x;                                  \
    const float sb = a0p.y + a1p.y + a2p.y;                                  \
    const bool ca = sa < 1e-2f, cb = sb < 1e-2f;                             \
    f32x2 m; m.x = ca ? 0x1p20f : 1.0f; m.y = cb ? 0x1p20f : 1.0f;           \
    a0p *= m; a1p *= m; a2p *= m;                                            \
    kka += ca ? 1 : 0; kkb += cb ? 1 : 0;                                    \
}

#define STEPP2(A0, B0, A1, B1) STEPP(A0, B0) STEPP(A1, B1) RESCALEP

__global__ __launch_bounds__(NTHR) void hmm_fwd_kernel(
    const float* __restrict__ Y,
    const float* __restrict__ Yo,
    const int*   __restrict__ Pi0,
    double*      __restrict__ partials,
    int nblk)
{
    // Per-thread, per-row-slot emission tables (e0,e2), SoA by code.
    // 7*2*256*8 = 28672 B -> 5 blocks/CU. Stride 8B columns: 2-way bank
    // aliasing = free. No barrier: each thread owns its column.
    __shared__ float2 sE[7][2][NTHR];

    // Reference quirk: E[b,1,5] = 1 - Ysa[1,3] for ALL b (batch row 1, col 3).
    const float fe15 = 1.0f - Y[1 * 13 + 3];   // uniform -> scalar
    const float pi0 = (float)Pi0[0];
    const float pi1 = (float)Pi0[1];
    const float pi2 = (float)Pi0[2];
    const int tid = threadIdx.x;

    const int r0 = blockIdx.x * NTHR + tid;
    const int r1 = r0 + HALF;

    // ---- obs rows: 8x float4 each, packed immediately to 4 u32 per row ----
    const float4* yo4a = reinterpret_cast<const float4*>(Yo + (size_t)r0 * T_LEN);
    const float4* yo4b = reinterpret_cast<const float4*>(Yo + (size_t)r1 * T_LEN);
    unsigned P0a, P1a, P2a, P3a, P0b, P1b, P2b, P3b;
    {
        const float4 w0 = yo4a[0], w1 = yo4a[1], w2 = yo4a[2], w3 = yo4a[3];
        const float4 w4 = yo4a[4], w5 = yo4a[5], w6 = yo4a[6], w7 = yo4a[7];
        P0a = pk4(w0) | (pk4(w1) << 16);
        P1a = pk4(w2) | (pk4(w3) << 16);
        P2a = pk4(w4) | (pk4(w5) << 16);
        P3a = pk4(w6) | (pk4(w7) << 16);
    }
    {
        const float4 w0 = yo4b[0], w1 = yo4b[1], w2 = yo4b[2], w3 = yo4b[3];
        const float4 w4 = yo4b[4], w5 = yo4b[5], w6 = yo4b[6], w7 = yo4b[7];
        P0b = pk4(w0) | (pk4(w1) << 16);
        P1b = pk4(w2) | (pk4(w3) << 16);
        P2b = pk4(w4) | (pk4(w5) << 16);
        P3b = pk4(w6) | (pk4(w7) << 16);
    }

    // ---- Y rows: params + table build per row-slot ----
    f32x2 t00p, t01p, t10p, t11p, t20p, t21p, t02p, t12p, t22p;
    float fy3a, fy3b;
    {
        const float* y = Y + (size_t)r0 * 13;
        const f32x4_a4 ya = *reinterpret_cast<const f32x4_a4*>(y + 0);
        const f32x4_a4 yb = *reinterpret_cast<const f32x4_a4*>(y + 4);
        const f32x4_a4 yc = *reinterpret_cast<const f32x4_a4*>(y + 8);
        const float    yd = y[12];
        const float fr03 = 1.0f - ya.x - ya.y - ya.z;
        const float fr23 = 1.0f - yb.x - yb.y - yb.z;
        sE[0][0][tid] = make_float2(ya.x, yb.x);
        sE[1][0][tid] = make_float2(ya.y, yb.y);
        sE[2][0][tid] = make_float2(ya.z, yb.z);
        sE[3][0][tid] = make_float2(fr03, fr23);
        sE[4][0][tid] = make_float2(0.0f, 0.0f);
        sE[5][0][tid] = make_float2(0.0f, 0.0f);
        sE[6][0][tid] = make_float2(1.0f, 1.0f);
        fy3a = ya.w;
        t00p.x = yb.w; t01p.x = yc.x;
        t10p.x = yc.y; t11p.x = yc.z;
        t20p.x = yc.w; t21p.x = yd;
        t02p.x = 1.0f - yb.w - yc.x;
        t12p.x = 1.0f - yc.y - yc.z;
        t22p.x = 1.0f - yc.w - yd;
    }
    {
        const float* y = Y + (size_t)r1 * 13;
        const f32x4_a4 ya = *reinterpret_cast<const f32x4_a4*>(y + 0);
        const f32x4_a4 yb = *reinterpret_cast<const f32x4_a4*>(y + 4);
        const f32x4_a4 yc = *reinterpret_cast<const f32x4_a4*>(y + 8);
        const float    yd = y[12];
        const float fr03 = 1.0f - ya.x - ya.y - ya.z;
        const float fr23 = 1.0f - yb.x - yb.y - yb.z;
        sE[0][1][tid] = make_float2(ya.x, yb.x);
        sE[1][1][tid] = make_float2(ya.y, yb.y);
        sE[2][1][tid] = make_float2(ya.z, yb.z);
        sE[3][1][tid] = make_float2(fr03, fr23);
        sE[4][1][tid] = make_float2(0.0f, 0.0f);
        sE[5][1][tid] = make_float2(0.0f, 0.0f);
        sE[6][1][tid] = make_float2(1.0f, 1.0f);
        fy3b = ya.w;
        t00p.y = yb.w; t01p.y = yc.x;
        t10p.y = yc.y; t11p.y = yc.z;
        t20p.y = yc.w; t21p.y = yd;
        t02p.y = 1.0f - yb.w - yc.x;
        t12p.y = 1.0f - yc.y - yc.z;
        t22p.y = 1.0f - yc.w - yd;
    }

    // ---- t = 0 init (always valid: length >= 4) ----
    f32x2 a0p, a1p, a2p;
    {
        const int oa = OC(P0a, 0), ob = OC(P0b, 0);
        const float2 ea = sE[oa][0][tid];
        const float2 eb = sE[ob][1][tid];
        f32x2 e0p; e0p.x = ea.x; e0p.y = eb.x;
        f32x2 e2p; e2p.x = ea.y; e2p.y = eb.y;
        f32x2 e1p;
        e1p.x = (oa==4)?fy3a:(oa==5)?fe15:0.0f;
        e1p.y = (ob==4)?fy3b:(ob==5)?fe15:0.0f;
        a0p = pi0 * e0p;
        a1p = pi1 * e1p;
        a2p = pi2 * e2p;
    }
    int kka = 0, kkb = 0;

    STEPP(OC(P0a,1), OC(P0b,1))                                   // t=1
    STEPP2(OC(P0a,2), OC(P0b,2), OC(P0a,3), OC(P0b,3))            // 2,3
    STEPP2(OC(P0a,4), OC(P0b,4), OC(P0a,5), OC(P0b,5))            // 4,5
    STEPP2(OC(P0a,6), OC(P0b,6), OC(P0a,7), OC(P0b,7))            // 6,7
    STEPP2(OC(P1a,0), OC(P1b,0), OC(P1a,1), OC(P1b,1))            // 8,9
    STEPP2(OC(P1a,2), OC(P1b,2), OC(P1a,3), OC(P1b,3))            // 10,11
    STEPP2(OC(P1a,4), OC(P1b,4), OC(P1a,5), OC(P1b,5))            // 12,13
    STEPP2(OC(P1a,6), OC(P1b,6), OC(P1a,7), OC(P1b,7))            // 14,15
    STEPP2(OC(P2a,0), OC(P2b,0), OC(P2a,1), OC(P2b,1))            // 16,17
    STEPP2(OC(P2a,2), OC(P2b,2), OC(P2a,3), OC(P2b,3))            // 18,19
    STEPP2(OC(P2a,4), OC(P2b,4), OC(P2a,5), OC(P2b,5))            // 20,21
    STEPP2(OC(P2a,6), OC(P2b,6), OC(P2a,7), OC(P2b,7))            // 22,23
    STEPP2(OC(P3a,0), OC(P3b,0), OC(P3a,1), OC(P3b,1))            // 24,25
    STEPP2(OC(P3a,2), OC(P3b,2), OC(P3a,3), OC(P3b,3))            // 26,27
    STEPP2(OC(P3a,4), OC(P3b,4), OC(P3a,5), OC(P3b,5))            // 28,29
    STEPP2(OC(P3a,6), OC(P3b,6), OC(P3a,7), OC(P3b,7))            // 30,31

    float sa = a0p.x + a1p.x + a2p.x;
    float sb = a0p.y + a1p.y + a2p.y;
    if (!(sa >= 1e-35f)) sa = 1e-35f;   // keep output finite (threshold-inf regime)
    if (!(sb >= 1e-35f)) sb = 1e-35f;
    double local = (double)logf(sa) + (double)logf(sb)
                 - (double)(kka + kkb) * (20.0 * 0.6931471805599453);

    // Block reduction (double): wave shuffle-reduce, then LDS across 4 waves.
    #pragma unroll
    for (int off = 32; off > 0; off >>= 1)
        local += __shfl_down(local, off, 64);
    __shared__ double sred[NTHR / 64];
    const int lane = threadIdx.x & 63;
    const int wv   = threadIdx.x >> 6;
    if (lane == 0) sred[wv] = local;
    __syncthreads();
    if (threadIdx.x == 0) {
        double s = 0.0;
        #pragma unroll
        for (int i = 0; i < NTHR / 64; ++i) s += sred[i];
        partials[blockIdx.x] = s;
    }
}

__global__ __launch_bounds__(256) void hmm_final_kernel(
    const double* __restrict__ partials, float* __restrict__ out, int nblk)
{
    double local = 0.0;
    for (int i = threadIdx.x; i < nblk; i += 256) local += partials[i];
    #pragma unroll
    for (int off = 32; off > 0; off >>= 1)
        local += __shfl_down(local, off, 64);
    __shared__ double sred[4];
    const int lane = threadIdx.x & 63;
    const int wv   = threadIdx.x >> 6;
    if (lane == 0) sred[wv] = local;
    __syncthreads();
    if (threadIdx.x == 0) {
        double s = sred[0] + sred[1] + sred[2] + sred[3];
        out[0] = (float)(-s / (double)B_ROWS);
    }
}

extern "C" void kernel_launch(void* const* d_in, const int* in_sizes, int n_in,
                              void* d_out, int out_size, void* d_ws, size_t ws_size,
                              hipStream_t stream)
{
    // Identify inputs by size rather than trusting order.
    const float* Y   = nullptr;   // (B, 13) f32
    const float* Yo  = nullptr;   // (B, 32) f32 (NaN-masked obs)
    const int*   Pi0 = nullptr;   // (3,) i32
    for (int i = 0; i < n_in; ++i) {
        if (in_sizes[i] == B_ROWS * 13)      Y   = (const float*)d_in[i];
        else if (in_sizes[i] == B_ROWS * 32) Yo  = (const float*)d_in[i];
        else if (in_sizes[i] == 3)           Pi0 = (const int*)d_in[i];
    }

    double* partials = (double*)d_ws;   // 2048 doubles = 16 KB

    hmm_fwd_kernel<<<NBLK, NTHR, 0, stream>>>(Y, Yo, Pi0, partials, NBLK);
    hmm_final_kernel<<<1, 256, 0, stream>>>(partials, (float*)d_out, NBLK);
}

// Round 12
// 45.026 us; speedup vs baseline: 1.3725x; 1.3725x over previous
//
#include <hip/hip_runtime.h>

static constexpr int B_ROWS = 1048576;
static constexpr int T_LEN  = 32;
static constexpr int NTHR   = 128;
static constexpr int NBLK   = B_ROWS / NTHR;   // 8192 blocks, 1 row/thread
static constexpr int TSTRIDE = 15;             // table stride in float4 (14 + pad)

typedef float f32x4 __attribute__((ext_vector_type(4)));
typedef f32x4 f32x4_a4 __attribute__((aligned(4)));

// Pack 4 obs floats into 4-bit codes. fminf(NaN, 6) == 6 -> sentinel in 1 op.
__device__ __forceinline__ unsigned pk4(const float4 v) {
    const unsigned o0 = (unsigned)(int)fminf(v.x, 6.0f);
    const unsigned o1 = (unsigned)(int)fminf(v.y, 6.0f);
    const unsigned o2 = (unsigned)(int)fminf(v.z, 6.0f);
    const unsigned o3 = (unsigned)(int)fminf(v.w, 6.0f);
    return o0 | (o1 << 4) | (o2 << 8) | (o3 << 12);
}

// One 2-state step: idx nibble T of IDXW selects the 2x2 matrix from LDS.
// 4 VALU, 2-deep dependency. ds_read address depends only on packed codes
// (not on the alpha chain) -> compiler can prefetch reads ahead.
#define STEPM(IDXW, T) {                                                     \
    const int idx = (int)(((IDXW) >> (4 * (T))) & 15u);                      \
    const f32x4 E = sM[tid15 + idx];                                         \
    const float u_ = E.x * p, v_ = E.z * p;                                  \
    p = fmaf(E.y, q, u_);                                                    \
    q = fmaf(E.w, q, v_);                                                    \
}

// Power-of-2 rescale every 2 steps on s = p + q; kk compensates exactly.
#define RESCALE {                                                            \
    const float s_ = p + q;                                                  \
    const bool sc = (s_ < 1e-2f);                                            \
    const float m_ = sc ? 0x1p20f : 1.0f;                                    \
    p *= m_; q *= m_;                                                        \
    kk += sc ? 1 : 0;                                                        \
}

#define STEPM2(W0, T0, W1, T1) STEPM(W0, T0) STEPM(W1, T1) RESCALE

__global__ __launch_bounds__(NTHR) void hmm_fwd_kernel(
    const float* __restrict__ Y,
    const float* __restrict__ Yo,
    const int*   __restrict__ Pi0,
    double*      __restrict__ partials)
{
    // Per-thread 14-entry float4 matrix table, stride 15 (240 B/thread ->
    // 60-dword column stride -> all 32 banks covered across 8 lanes ->
    // conflict-free ds_read_b128). 30720 B/block -> 5 blocks/CU.
    // No barrier: each thread owns its column.
    __shared__ f32x4 sM[NTHR * TSTRIDE];

    // Reference quirk: E[b,1,5] = 1 - Ysa[1,3] for ALL b (batch row 1, col 3).
    const float fe15 = 1.0f - Y[1 * 13 + 3];   // uniform -> scalar load
    const float pi0 = (float)Pi0[0];
    const float pi1 = (float)Pi0[1];
    const float pi2 = (float)Pi0[2];
    const int tid   = threadIdx.x;
    const int tid15 = tid * TSTRIDE;

    const int r = blockIdx.x * NTHR + tid;

    // ---- obs row: 8x float4, packed immediately to 4 u32 ----
    const float4* yo4 = reinterpret_cast<const float4*>(Yo + (size_t)r * T_LEN);
    const float4 w0 = yo4[0], w1 = yo4[1], w2 = yo4[2], w3 = yo4[3];
    const float4 w4 = yo4[4], w5 = yo4[5], w6 = yo4[6], w7 = yo4[7];
    const int o0 = (int)w0.x;                  // t=0 obs, never NaN (len >= 4)
    const unsigned P0 = pk4(w0) | (pk4(w1) << 16);
    const unsigned P1 = pk4(w2) | (pk4(w3) << 16);
    const unsigned P2 = pk4(w4) | (pk4(w5) << 16);
    const unsigned P3 = pk4(w6) | (pk4(w7) << 16);

    // Combined table index per step: idx_t = o_t + 7*(o_{t-1} >= 4).
    // Contiguous NaN tail => for alive steps o_{t-1} != 6, so prev-mode is
    // just bit2 of the prev code; for dead steps both idx 6/13 are identity.
    // Nibble math: ge4 = bit2 of prev nibble; idx = o + 8*ge4 - ge4 (<= 13,
    // no nibble carries since o<=6 and +8 then -1 stays within the nibble).
    const unsigned PR0 = (P0 << 4);                     // nibble t = o_{t-1}
    const unsigned PR1 = (P1 << 4) | (P0 >> 28);
    const unsigned PR2 = (P2 << 4) | (P1 >> 28);
    const unsigned PR3 = (P3 << 4) | (P2 >> 28);
    const unsigned G0 = (PR0 >> 2) & 0x11111111u;
    const unsigned G1 = (PR1 >> 2) & 0x11111111u;
    const unsigned G2 = (PR2 >> 2) & 0x11111111u;
    const unsigned G3 = (PR3 >> 2) & 0x11111111u;
    const unsigned I0 = P0 + (G0 << 3) - G0;
    const unsigned I1 = P1 + (G1 << 3) - G1;
    const unsigned I2 = P2 + (G2 << 3) - G2;
    const unsigned I3 = P3 + (G3 << 3) - G3;

    // ---- Y row: 13 floats -> 3 x dwordx4 + 1 dword ----
    const float* y = Y + (size_t)r * 13;
    const f32x4_a4 ya = *reinterpret_cast<const f32x4_a4*>(y + 0);
    const f32x4_a4 yb = *reinterpret_cast<const f32x4_a4*>(y + 4);
    const f32x4_a4 yc = *reinterpret_cast<const f32x4_a4*>(y + 8);
    const float    yd = y[12];
    const float fy0 = ya.x, fy1 = ya.y, fy2 = ya.z, fy3 = ya.w;
    const float fy4 = yb.x, fy5 = yb.y, fy6 = yb.z;
    const float fr03 = 1.0f - fy0 - fy1 - fy2;
    const float fr23 = 1.0f - fy4 - fy5 - fy6;
    const float t00 = yb.w, t01 = yc.x;
    const float t10 = yc.y, t11 = yc.z;
    const float t20 = yc.w, t21 = yd;
    const float t02 = 1.0f - t00 - t01;
    const float t12 = 1.0f - t10 - t11;
    const float t22 = 1.0f - t20 - t21;

    // ---- build the 14-entry 2x2 matrix table (exact zeros in dead slots) --
    // AC-target (o<4), prev AC:  [t00*e0, t20*e0, t02*e2, t22*e2]
    // AC-target (o<4), prev B:   [t10*e0,      0, t12*e2,      0]
    // B-target (o in 4,5), AC:   [t01*e1, t21*e1,      0,      0]
    // B-target (o in 4,5), B:    [t11*e1,      0,      0,      0]
    // dead (o=6), either mode:   [1, 0, 0, 1]   (exact freeze)
    {
        f32x4 e;
        e.x = t00*fy0;  e.y = t20*fy0;  e.z = t02*fy4;  e.w = t22*fy4;  sM[tid15+0]  = e;
        e.x = t00*fy1;  e.y = t20*fy1;  e.z = t02*fy5;  e.w = t22*fy5;  sM[tid15+1]  = e;
        e.x = t00*fy2;  e.y = t20*fy2;  e.z = t02*fy6;  e.w = t22*fy6;  sM[tid15+2]  = e;
        e.x = t00*fr03; e.y = t20*fr03; e.z = t02*fr23; e.w = t22*fr23; sM[tid15+3]  = e;
        e.x = t01*fy3;  e.y = t21*fy3;  e.z = 0.0f;     e.w = 0.0f;     sM[tid15+4]  = e;
        e.x = t01*fe15; e.y = t21*fe15; e.z = 0.0f;     e.w = 0.0f;     sM[tid15+5]  = e;
        e.x = 1.0f;     e.y = 0.0f;     e.z = 0.0f;     e.w = 1.0f;     sM[tid15+6]  = e;
        e.x = t10*fy0;  e.y = 0.0f;     e.z = t12*fy4;  e.w = 0.0f;     sM[tid15+7]  = e;
        e.x = t10*fy1;  e.y = 0.0f;     e.z = t12*fy5;  e.w = 0.0f;     sM[tid15+8]  = e;
        e.x = t10*fy2;  e.y = 0.0f;     e.z = t12*fy6;  e.w = 0.0f;     sM[tid15+9]  = e;
        e.x = t10*fr03; e.y = 0.0f;     e.z = t12*fr23; e.w = 0.0f;     sM[tid15+10] = e;
        e.x = t11*fy3;  e.y = 0.0f;     e.z = 0.0f;     e.w = 0.0f;     sM[tid15+11] = e;
        e.x = t11*fe15; e.y = 0.0f;     e.z = 0.0f;     e.w = 0.0f;     sM[tid15+12] = e;
        e.x = 1.0f;     e.y = 0.0f;     e.z = 0.0f;     e.w = 1.0f;     sM[tid15+13] = e;
    }

    // ---- t = 0 init: alpha_0 = Pi o E(o0); already mode-structured ----
    float p, q;
    {
        const float e0i = (o0==0)?fy0:(o0==1)?fy1:(o0==2)?fy2:fr03;
        const float e2i = (o0==0)?fy4:(o0==1)?fy5:(o0==2)?fy6:fr23;
        const float e1i = (o0==4)?fy3:fe15;
        const bool m0 = (o0 >= 4);
        p = m0 ? pi1 * e1i : pi0 * e0i;
        q = m0 ? 0.0f      : pi2 * e2i;
    }
    int kk = 0;

    STEPM(I0, 1)                       // t=1
    STEPM2(I0, 2, I0, 3)               // 2,3
    STEPM2(I0, 4, I0, 5)               // 4,5
    STEPM2(I0, 6, I0, 7)               // 6,7
    STEPM2(I1, 0, I1, 1)               // 8,9
    STEPM2(I1, 2, I1, 3)               // 10,11
    STEPM2(I1, 4, I1, 5)               // 12,13
    STEPM2(I1, 6, I1, 7)               // 14,15
    STEPM2(I2, 0, I2, 1)               // 16,17
    STEPM2(I2, 2, I2, 3)               // 18,19
    STEPM2(I2, 4, I2, 5)               // 20,21
    STEPM2(I2, 6, I2, 7)               // 22,23
    STEPM2(I3, 0, I3, 1)               // 24,25
    STEPM2(I3, 2, I3, 3)               // 26,27
    STEPM2(I3, 4, I3, 5)               // 28,29
    STEPM2(I3, 6, I3, 7)               // 30,31

    float s = p + q;                   // == a0+a1+a2 in both modes
    // Guard: exact-0/NaN -> clamp so output stays finite (threshold-inf regime).
    if (!(s >= 1e-35f)) s = 1e-35f;
    double local = (double)logf(s)
                 - (double)kk * (20.0 * 0.6931471805599453);

    // Block reduction (double): wave shuffle-reduce, then LDS across 2 waves.
    #pragma unroll
    for (int off = 32; off > 0; off >>= 1)
        local += __shfl_down(local, off, 64);
    __shared__ double sred[NTHR / 64];
    const int lane = tid & 63;
    const int wv   = tid >> 6;
    if (lane == 0) sred[wv] = local;
    __syncthreads();
    if (tid == 0)
        partials[blockIdx.x] = sred[0] + sred[1];
}

__global__ __launch_bounds__(256) void hmm_final_kernel(
    const double* __restrict__ partials, float* __restrict__ out, int nblk)
{
    double local = 0.0;
    for (int i = threadIdx.x; i < nblk; i += 256) local += partials[i];
    #pragma unroll
    for (int off = 32; off > 0; off >>= 1)
        local += __shfl_down(local, off, 64);
    __shared__ double sred[4];
    const int lane = threadIdx.x & 63;
    const int wv   = threadIdx.x >> 6;
    if (lane == 0) sred[wv] = local;
    __syncthreads();
    if (threadIdx.x == 0) {
        double s = sred[0] + sred[1] + sred[2] + sred[3];
        out[0] = (float)(-s / (double)B_ROWS);
    }
}

extern "C" void kernel_launch(void* const* d_in, const int* in_sizes, int n_in,
                              void* d_out, int out_size, void* d_ws, size_t ws_size,
                              hipStream_t stream)
{
    // Identify inputs by size rather than trusting order.
    const float* Y   = nullptr;   // (B, 13) f32
    const float* Yo  = nullptr;   // (B, 32) f32 (NaN-masked obs)
    const int*   Pi0 = nullptr;   // (3,) i32
    for (int i = 0; i < n_in; ++i) {
        if (in_sizes[i] == B_ROWS * 13)      Y   = (const float*)d_in[i];
        else if (in_sizes[i] == B_ROWS * 32) Yo  = (const float*)d_in[i];
        else if (in_sizes[i] == 3)           Pi0 = (const int*)d_in[i];
    }

    double* partials = (double*)d_ws;   // 8192 doubles = 64 KB

    hmm_fwd_kernel<<<NBLK, NTHR, 0, stream>>>(Y, Yo, Pi0, partials);
    hmm_final_kernel<<<1, 256, 0, stream>>>(partials, (float*)d_out, NBLK);
}

// Round 13
// 40.290 us; speedup vs baseline: 1.5338x; 1.1176x over previous
//
#include <hip/hip_runtime.h>

static constexpr int B_ROWS = 1048576;
static constexpr int T_LEN  = 32;
static constexpr int NTHR   = 256;
static constexpr int NBLK   = B_ROWS / NTHR;   // 4096 blocks, 1 row/thread

// Pack 4 obs floats into 4-bit codes. fminf(NaN, 6) == 6 -> sentinel in 1 op.
__device__ __forceinline__ unsigned pk4(const float4 v) {
    const unsigned o0 = (unsigned)(int)fminf(v.x, 6.0f);
    const unsigned o1 = (unsigned)(int)fminf(v.y, 6.0f);
    const unsigned o2 = (unsigned)(int)fminf(v.z, 6.0f);
    const unsigned o3 = (unsigned)(int)fminf(v.w, 6.0f);
    return o0 | (o1 << 4) | (o2 << 8) | (o3 << 12);
}
#define OC(P, I) ((int)(((P) >> (4 * (I))) & 7u))

// One HMM step: emissions from split LDS tables (float2 e0/e2 + float e1).
// Code 6 (past end) has emissions (1,1,1): T rows sum to 1, so a dead step
// preserves sum(alpha) exactly -> same log(sum) as the frozen-alpha reference.
#define HMM_STEP(O) {                                                        \
    const int o_ = (O);                                                      \
    const float2 exz = sE2[o_ * NTHR + tid];                                 \
    const float  e1  = sE1[o_ * NTHR + tid];                                 \
    const float n0 = (a0*t00 + a1*t10 + a2*t20) * exz.x;                     \
    const float n1 = (a0*t01 + a1*t11 + a2*t21) * e1;                        \
    const float n2 = (a0*t02 + a1*t12 + a2*t22) * exz.y;                     \
    a0 = n0; a1 = n1; a2 = n2;                                               \
}

// Power-of-2 rescale every 2 steps; self-limits after row death (sum
// preserved), exactly compensated by kk.
#define RESCALE {                                                            \
    const float s_ = a0 + a1 + a2;                                           \
    const bool sc = (s_ < 1e-2f);                                            \
    const float m_ = sc ? 0x1p20f : 1.0f;                                    \
    a0 *= m_; a1 *= m_; a2 *= m_;                                            \
    kk += sc ? 1 : 0;                                                        \
}

#define STEP2(A, B) HMM_STEP(A) HMM_STEP(B) RESCALE

__global__ __launch_bounds__(NTHR) void hmm_fwd_kernel(
    const float* __restrict__ Y,
    const float* __restrict__ Yo,
    const int*   __restrict__ Pi0,
    double*      __restrict__ partials)
{
    // One 32 KB region, used in 3 sequential phases (barrier-separated):
    //   phase 1: Yo staging, 256 rows x 128 B, 16B-slot XOR swizzle
    //   phase 2: Y staging, flat 13*256 floats
    //   phase 3: split emission tables (21.5 KB), own-column, no barrier
    __shared__ float4 sBuf[NTHR * 8];
    float2* sE2 = reinterpret_cast<float2*>(sBuf);                 // [7][NTHR]
    float*  sE1 = reinterpret_cast<float*>(sBuf) + 7 * NTHR * 2;   // [7][NTHR]
    float*  sY  = reinterpret_cast<float*>(sBuf);                  // [13*NTHR]

    // Reference quirk: E[b,1,5] = 1 - Ysa[1,3] for ALL b (batch row 1, col 3).
    const float fe15 = 1.0f - Y[1 * 13 + 3];   // uniform -> scalar load
    const float pi0 = (float)Pi0[0];
    const float pi1 = (float)Pi0[1];
    const float pi2 = (float)Pi0[2];
    const int tid = threadIdx.x;
    const size_t blockRow = (size_t)blockIdx.x * NTHR;

    // ---- Phase 1: stage Yo coalesced (1 KB contiguous per wave instr) ----
    {
        const float4* g = reinterpret_cast<const float4*>(Yo + blockRow * T_LEN);
        #pragma unroll
        for (int k = 0; k < 8; ++k) {
            const int gidx = k * NTHR + tid;           // coalesced source
            const int r = gidx >> 3, s = gidx & 7;
            sBuf[r * 8 + (s ^ (r & 7))] = g[gidx];     // swizzled dest
        }
    }
    __syncthreads();

    // ---- Phase 1b: read own row from LDS (swizzled), pack codes ----
    unsigned P0, P1, P2, P3;
    int o0;
    {
        const int x = tid & 7;
        const int base = tid * 8;
        const float4 w0 = sBuf[base + (0 ^ x)];
        const float4 w1 = sBuf[base + (1 ^ x)];
        const float4 w2 = sBuf[base + (2 ^ x)];
        const float4 w3 = sBuf[base + (3 ^ x)];
        const float4 w4 = sBuf[base + (4 ^ x)];
        const float4 w5 = sBuf[base + (5 ^ x)];
        const float4 w6 = sBuf[base + (6 ^ x)];
        const float4 w7 = sBuf[base + (7 ^ x)];
        o0 = (int)w0.x;                      // t=0 obs, never NaN (len >= 4)
        P0 = pk4(w0) | (pk4(w1) << 16);
        P1 = pk4(w2) | (pk4(w3) << 16);
        P2 = pk4(w4) | (pk4(w5) << 16);
        P3 = pk4(w6) | (pk4(w7) << 16);
    }
    __syncthreads();

    // ---- Phase 2: stage Y coalesced (flat copy keeps [row][13] layout) ----
    {
        const float* g = Y + blockRow * 13;
        #pragma unroll
        for (int k = 0; k < 13; ++k)
            sY[k * NTHR + tid] = g[k * NTHR + tid];
    }
    __syncthreads();

    // ---- Phase 2b: read own params (stride 13, odd -> conflict-free) ----
    const float* yrow = &sY[tid * 13];
    const float fy0 = yrow[0], fy1 = yrow[1], fy2 = yrow[2], fy3 = yrow[3];
    const float fy4 = yrow[4], fy5 = yrow[5], fy6 = yrow[6];
    const float t00 = yrow[7],  t01 = yrow[8];
    const float t10 = yrow[9],  t11 = yrow[10];
    const float t20 = yrow[11], t21 = yrow[12];
    const float fr03 = 1.0f - fy0 - fy1 - fy2;
    const float fr23 = 1.0f - fy4 - fy5 - fy6;
    const float t02 = 1.0f - t00 - t01;
    const float t12 = 1.0f - t10 - t11;
    const float t22 = 1.0f - t20 - t21;
    __syncthreads();

    // ---- Phase 3: build split emission tables (own column, no barrier) ----
    sE2[0 * NTHR + tid] = make_float2(fy0,  fy4);
    sE2[1 * NTHR + tid] = make_float2(fy1,  fy5);
    sE2[2 * NTHR + tid] = make_float2(fy2,  fy6);
    sE2[3 * NTHR + tid] = make_float2(fr03, fr23);
    sE2[4 * NTHR + tid] = make_float2(0.0f, 0.0f);
    sE2[5 * NTHR + tid] = make_float2(0.0f, 0.0f);
    sE2[6 * NTHR + tid] = make_float2(1.0f, 1.0f);
    sE1[0 * NTHR + tid] = 0.0f;
    sE1[1 * NTHR + tid] = 0.0f;
    sE1[2 * NTHR + tid] = 0.0f;
    sE1[3 * NTHR + tid] = 0.0f;
    sE1[4 * NTHR + tid] = fy3;
    sE1[5 * NTHR + tid] = fe15;
    sE1[6 * NTHR + tid] = 1.0f;

    // ---- t = 0 init (always valid: length >= 4) ----
    float a0, a1, a2;
    {
        const float2 exz = sE2[o0 * NTHR + tid];
        const float  e1  = sE1[o0 * NTHR + tid];
        a0 = pi0 * exz.x;
        a1 = pi1 * e1;
        a2 = pi2 * exz.y;
    }
    int kk = 0;

    HMM_STEP(OC(P0, 1))                    // t=1
    STEP2(OC(P0, 2), OC(P0, 3))            // t=2,3
    STEP2(OC(P0, 4), OC(P0, 5))            // 4,5
    STEP2(OC(P0, 6), OC(P0, 7))            // 6,7
    STEP2(OC(P1, 0), OC(P1, 1))            // 8,9
    STEP2(OC(P1, 2), OC(P1, 3))            // 10,11
    STEP2(OC(P1, 4), OC(P1, 5))            // 12,13
    STEP2(OC(P1, 6), OC(P1, 7))            // 14,15
    STEP2(OC(P2, 0), OC(P2, 1))            // 16,17
    STEP2(OC(P2, 2), OC(P2, 3))            // 18,19
    STEP2(OC(P2, 4), OC(P2, 5))            // 20,21
    STEP2(OC(P2, 6), OC(P2, 7))            // 22,23
    STEP2(OC(P3, 0), OC(P3, 1))            // 24,25
    STEP2(OC(P3, 2), OC(P3, 3))            // 26,27
    STEP2(OC(P3, 4), OC(P3, 5))            // 28,29
    STEP2(OC(P3, 6), OC(P3, 7))            // 30,31

    float asum = a0 + a1 + a2;
    // Guard: exact-0/NaN alpha-sum -> clamp so output stays finite.
    if (!(asum >= 1e-35f)) asum = 1e-35f;
    double local = (double)logf(asum)
                 - (double)kk * (20.0 * 0.6931471805599453);

    // Block reduction (double): wave shuffle-reduce, then LDS across 4 waves.
    #pragma unroll
    for (int off = 32; off > 0; off >>= 1)
        local += __shfl_down(local, off, 64);
    __shared__ double sred[NTHR / 64];
    const int lane = tid & 63;
    const int wv   = tid >> 6;
    if (lane == 0) sred[wv] = local;
    __syncthreads();
    if (tid == 0) {
        double s = 0.0;
        #pragma unroll
        for (int i = 0; i < NTHR / 64; ++i) s += sred[i];
        partials[blockIdx.x] = s;
    }
}

__global__ __launch_bounds__(256) void hmm_final_kernel(
    const double* __restrict__ partials, float* __restrict__ out, int nblk)
{
    double local = 0.0;
    for (int i = threadIdx.x; i < nblk; i += 256) local += partials[i];
    #pragma unroll
    for (int off = 32; off > 0; off >>= 1)
        local += __shfl_down(local, off, 64);
    __shared__ double sred[4];
    const int lane = threadIdx.x & 63;
    const int wv   = threadIdx.x >> 6;
    if (lane == 0) sred[wv] = local;
    __syncthreads();
    if (threadIdx.x == 0) {
        double s = sred[0] + sred[1] + sred[2] + sred[3];
        out[0] = (float)(-s / (double)B_ROWS);
    }
}

extern "C" void kernel_launch(void* const* d_in, const int* in_sizes, int n_in,
                              void* d_out, int out_size, void* d_ws, size_t ws_size,
                              hipStream_t stream)
{
    // Identify inputs by size rather than trusting order.
    const float* Y   = nullptr;   // (B, 13) f32
    const float* Yo  = nullptr;   // (B, 32) f32 (NaN-masked obs)
    const int*   Pi0 = nullptr;   // (3,) i32
    for (int i = 0; i < n_in; ++i) {
        if (in_sizes[i] == B_ROWS * 13)      Y   = (const float*)d_in[i];
        else if (in_sizes[i] == B_ROWS * 32) Yo  = (const float*)d_in[i];
        else if (in_sizes[i] == 3)           Pi0 = (const int*)d_in[i];
    }

    double* partials = (double*)d_ws;   // 4096 doubles = 32 KB

    hmm_fwd_kernel<<<NBLK, NTHR, 0, stream>>>(Y, Yo, Pi0, partials);
    hmm_final_kernel<<<1, 256, 0, stream>>>(partials, (float*)d_out, NBLK);
}

// Round 14
// 40.169 us; speedup vs baseline: 1.5384x; 1.0030x over previous
//
#include <hip/hip_runtime.h>

static constexpr int B_ROWS = 1048576;
static constexpr int T_LEN  = 32;
static constexpr int NTHR   = 256;
static constexpr int NBLK   = B_ROWS / NTHR;   // 4096 blocks, 1 row/thread

typedef float f32x4 __attribute__((ext_vector_type(4)));
typedef f32x4 f32x4_a4 __attribute__((aligned(4)));

// Pack 4 obs floats into 4-bit codes. fminf(NaN, 6) == 6 -> sentinel in 1 op.
__device__ __forceinline__ unsigned pk4(const float4 v) {
    const unsigned o0 = (unsigned)(int)fminf(v.x, 6.0f);
    const unsigned o1 = (unsigned)(int)fminf(v.y, 6.0f);
    const unsigned o2 = (unsigned)(int)fminf(v.z, 6.0f);
    const unsigned o3 = (unsigned)(int)fminf(v.w, 6.0f);
    return o0 | (o1 << 4) | (o2 << 8) | (o3 << 12);
}

// One 2-state step: nibble T of IDXW selects the combined 2x2 matrix.
// Layout sM[idx*NTHR + tid]: entry index shifts by 1024 dwords == 0 mod 32
// banks -> divergent idx never changes bank mapping (R9 measured 0 conflicts
// on this exact pattern). 4 VALU, 2-deep chain; ds_read address depends only
// on packed codes -> pipelines ahead of the alpha chain.
#define STEPM(IDXW, T) {                                                     \
    const int idx = (int)(((IDXW) >> (4 * (T))) & 15u);                      \
    const f32x4 E = sM[idx * NTHR + tid];                                    \
    const float u_ = E.x * p, v_ = E.z * p;                                  \
    p = fmaf(E.y, q, u_);                                                    \
    q = fmaf(E.w, q, v_);                                                    \
}

// Power-of-2 rescale every 2 steps on s = p + q; kk compensates exactly.
// Self-limits after row death (identity steps preserve p,q).
#define RESCALE {                                                            \
    const float s_ = p + q;                                                  \
    const bool sc = (s_ < 1e-2f);                                            \
    const float m_ = sc ? 0x1p20f : 1.0f;                                    \
    p *= m_; q *= m_;                                                        \
    kk += sc ? 1 : 0;                                                        \
}

#define STEPM2(W0, T0, W1, T1) STEPM(W0, T0) STEPM(W1, T1) RESCALE

__global__ __launch_bounds__(NTHR) void hmm_fwd_kernel(
    const float* __restrict__ Y,
    const float* __restrict__ Yo,
    const int*   __restrict__ Pi0,
    double*      __restrict__ partials)
{
    // 13-entry combined (obs, prev-mode) 2x2 matrix table, [entry][NTHR]:
    // 13*256*16 = 52 KB -> 3 blocks/CU -> 24 waves/CU (75% ceiling).
    // No barrier: each thread owns its column.
    __shared__ f32x4 sM[13 * NTHR];

    // Reference quirk: E[b,1,5] = 1 - Ysa[1,3] for ALL b (batch row 1, col 3).
    const float fe15 = 1.0f - Y[1 * 13 + 3];   // uniform -> scalar load
    const float pi0 = (float)Pi0[0];
    const float pi1 = (float)Pi0[1];
    const float pi2 = (float)Pi0[2];
    const int tid = threadIdx.x;

    const int r = blockIdx.x * NTHR + tid;

    // ---- obs row: 8x float4, packed immediately to 4 u32 ----
    const float4* yo4 = reinterpret_cast<const float4*>(Yo + (size_t)r * T_LEN);
    const float4 w0 = yo4[0], w1 = yo4[1], w2 = yo4[2], w3 = yo4[3];
    const float4 w4 = yo4[4], w5 = yo4[5], w6 = yo4[6], w7 = yo4[7];
    const int o0 = (int)w0.x;                  // t=0 obs, never NaN (len >= 4)
    const unsigned P0 = pk4(w0) | (pk4(w1) << 16);
    const unsigned P1 = pk4(w2) | (pk4(w3) << 16);
    const unsigned P2 = pk4(w4) | (pk4(w5) << 16);
    const unsigned P3 = pk4(w6) | (pk4(w7) << 16);

    // Combined index per step: idx_t = o_t + 7*(o_{t-1} >= 4), except o_t == 6
    // always maps to the single identity entry 6 (prev-mode masked off).
    // ge4 = bit2 of prev nibble; is6 = bits2&1 of CURRENT nibble (only value 6
    // has both among codes 0..6). idx = o + 8g - g, no nibble carries.
    const unsigned PR0 = (P0 << 4);                     // nibble t = o_{t-1}
    const unsigned PR1 = (P1 << 4) | (P0 >> 28);
    const unsigned PR2 = (P2 << 4) | (P1 >> 28);
    const unsigned PR3 = (P3 << 4) | (P2 >> 28);
    const unsigned M60 = ((P0 >> 1) & (P0 >> 2)) & 0x11111111u;
    const unsigned M61 = ((P1 >> 1) & (P1 >> 2)) & 0x11111111u;
    const unsigned M62 = ((P2 >> 1) & (P2 >> 2)) & 0x11111111u;
    const unsigned M63 = ((P3 >> 1) & (P3 >> 2)) & 0x11111111u;
    const unsigned G0 = ((PR0 >> 2) & 0x11111111u) & ~M60;
    const unsigned G1 = ((PR1 >> 2) & 0x11111111u) & ~M61;
    const unsigned G2 = ((PR2 >> 2) & 0x11111111u) & ~M62;
    const unsigned G3 = ((PR3 >> 2) & 0x11111111u) & ~M63;
    const unsigned I0 = P0 + (G0 << 3) - G0;
    const unsigned I1 = P1 + (G1 << 3) - G1;
    const unsigned I2 = P2 + (G2 << 3) - G2;
    const unsigned I3 = P3 + (G3 << 3) - G3;

    // ---- Y row: 13 floats -> 3 x dwordx4 + 1 dword ----
    const float* y = Y + (size_t)r * 13;
    const f32x4_a4 ya = *reinterpret_cast<const f32x4_a4*>(y + 0);
    const f32x4_a4 yb = *reinterpret_cast<const f32x4_a4*>(y + 4);
    const f32x4_a4 yc = *reinterpret_cast<const f32x4_a4*>(y + 8);
    const float    yd = y[12];
    const float fy0 = ya.x, fy1 = ya.y, fy2 = ya.z, fy3 = ya.w;
    const float fy4 = yb.x, fy5 = yb.y, fy6 = yb.z;
    const float fr03 = 1.0f - fy0 - fy1 - fy2;
    const float fr23 = 1.0f - fy4 - fy5 - fy6;
    const float t00 = yb.w, t01 = yc.x;
    const float t10 = yc.y, t11 = yc.z;
    const float t20 = yc.w, t21 = yd;
    const float t02 = 1.0f - t00 - t01;
    const float t12 = 1.0f - t10 - t11;
    const float t22 = 1.0f - t20 - t21;

    // ---- build the 13-entry table (exact zeros; entry 6 = exact identity) --
    // 0..3   AC<-AC : [t00*e0, t20*e0, t02*e2, t22*e2]
    // 4..5   B <-AC : [t01*e1, t21*e1, 0, 0]
    // 6      dead   : [1, 0, 0, 1]
    // 7..10  AC<-B  : [t10*e0, 0, t12*e2, 0]
    // 11..12 B <-B  : [t11*e1, 0, 0, 0]
    {
        f32x4 e;
        e.x = t00*fy0;  e.y = t20*fy0;  e.z = t02*fy4;  e.w = t22*fy4;  sM[ 0*NTHR+tid] = e;
        e.x = t00*fy1;  e.y = t20*fy1;  e.z = t02*fy5;  e.w = t22*fy5;  sM[ 1*NTHR+tid] = e;
        e.x = t00*fy2;  e.y = t20*fy2;  e.z = t02*fy6;  e.w = t22*fy6;  sM[ 2*NTHR+tid] = e;
        e.x = t00*fr03; e.y = t20*fr03; e.z = t02*fr23; e.w = t22*fr23; sM[ 3*NTHR+tid] = e;
        e.x = t01*fy3;  e.y = t21*fy3;  e.z = 0.0f;     e.w = 0.0f;     sM[ 4*NTHR+tid] = e;
        e.x = t01*fe15; e.y = t21*fe15; e.z = 0.0f;     e.w = 0.0f;     sM[ 5*NTHR+tid] = e;
        e.x = 1.0f;     e.y = 0.0f;     e.z = 0.0f;     e.w = 1.0f;     sM[ 6*NTHR+tid] = e;
        e.x = t10*fy0;  e.y = 0.0f;     e.z = t12*fy4;  e.w = 0.0f;     sM[ 7*NTHR+tid] = e;
        e.x = t10*fy1;  e.y = 0.0f;     e.z = t12*fy5;  e.w = 0.0f;     sM[ 8*NTHR+tid] = e;
        e.x = t10*fy2;  e.y = 0.0f;     e.z = t12*fy6;  e.w = 0.0f;     sM[ 9*NTHR+tid] = e;
        e.x = t10*fr03; e.y = 0.0f;     e.z = t12*fr23; e.w = 0.0f;     sM[10*NTHR+tid] = e;
        e.x = t11*fy3;  e.y = 0.0f;     e.z = 0.0f;     e.w = 0.0f;     sM[11*NTHR+tid] = e;
        e.x = t11*fe15; e.y = 0.0f;     e.z = 0.0f;     e.w = 0.0f;     sM[12*NTHR+tid] = e;
    }

    // ---- t = 0 init: (p,q) mode-structured; o0 in 0..5 ----
    float p, q;
    {
        const float e0i = (o0==0)?fy0:(o0==1)?fy1:(o0==2)?fy2:fr03;
        const float e2i = (o0==0)?fy4:(o0==1)?fy5:(o0==2)?fy6:fr23;
        const float e1i = (o0==4)?fy3:fe15;
        const bool m0 = (o0 >= 4);
        p = m0 ? pi1 * e1i : pi0 * e0i;
        q = m0 ? 0.0f      : pi2 * e2i;
    }
    int kk = 0;

    STEPM(I0, 1)                       // t=1
    STEPM2(I0, 2, I0, 3)               // 2,3
    STEPM2(I0, 4, I0, 5)               // 4,5
    STEPM2(I0, 6, I0, 7)               // 6,7
    STEPM2(I1, 0, I1, 1)               // 8,9
    STEPM2(I1, 2, I1, 3)               // 10,11
    STEPM2(I1, 4, I1, 5)               // 12,13
    STEPM2(I1, 6, I1, 7)               // 14,15
    STEPM2(I2, 0, I2, 1)               // 16,17
    STEPM2(I2, 2, I2, 3)               // 18,19
    STEPM2(I2, 4, I2, 5)               // 20,21
    STEPM2(I2, 6, I2, 7)               // 22,23
    STEPM2(I3, 0, I3, 1)               // 24,25
    STEPM2(I3, 2, I3, 3)               // 26,27
    STEPM2(I3, 4, I3, 5)               // 28,29
    STEPM2(I3, 6, I3, 7)               // 30,31

    float s = p + q;                   // == a0+a1+a2 in both modes
    // Guard: exact-0/NaN -> clamp so output stays finite (threshold-inf regime).
    if (!(s >= 1e-35f)) s = 1e-35f;
    double local = (double)logf(s)
                 - (double)kk * (20.0 * 0.6931471805599453);

    // Block reduction (double): wave shuffle-reduce, then LDS across 4 waves.
    #pragma unroll
    for (int off = 32; off > 0; off >>= 1)
        local += __shfl_down(local, off, 64);
    __shared__ double sred[NTHR / 64];
    const int lane = tid & 63;
    const int wv   = tid >> 6;
    if (lane == 0) sred[wv] = local;
    __syncthreads();
    if (tid == 0) {
        double ssum = 0.0;
        #pragma unroll
        for (int i = 0; i < NTHR / 64; ++i) ssum += sred[i];
        partials[blockIdx.x] = ssum;
    }
}

__global__ __launch_bounds__(256) void hmm_final_kernel(
    const double* __restrict__ partials, float* __restrict__ out, int nblk)
{
    double local = 0.0;
    for (int i = threadIdx.x; i < nblk; i += 256) local += partials[i];
    #pragma unroll
    for (int off = 32; off > 0; off >>= 1)
        local += __shfl_down(local, off, 64);
    __shared__ double sred[4];
    const int lane = threadIdx.x & 63;
    const int wv   = threadIdx.x >> 6;
    if (lane == 0) sred[wv] = local;
    __syncthreads();
    if (threadIdx.x == 0) {
        double s = sred[0] + sred[1] + sred[2] + sred[3];
        out[0] = (float)(-s / (double)B_ROWS);
    }
}

extern "C" void kernel_launch(void* const* d_in, const int* in_sizes, int n_in,
                              void* d_out, int out_size, void* d_ws, size_t ws_size,
                              hipStream_t stream)
{
    // Identify inputs by size rather than trusting order.
    const float* Y   = nullptr;   // (B, 13) f32
    const float* Yo  = nullptr;   // (B, 32) f32 (NaN-masked obs)
    const int*   Pi0 = nullptr;   // (3,) i32
    for (int i = 0; i < n_in; ++i) {
        if (in_sizes[i] == B_ROWS * 13)      Y   = (const float*)d_in[i];
        else if (in_sizes[i] == B_ROWS * 32) Yo  = (const float*)d_in[i];
        else if (in_sizes[i] == 3)           Pi0 = (const int*)d_in[i];
    }

    double* partials = (double*)d_ws;   // 4096 doubles = 32 KB

    hmm_fwd_kernel<<<NBLK, NTHR, 0, stream>>>(Y, Yo, Pi0, partials);
    hmm_final_kernel<<<1, 256, 0, stream>>>(partials, (float*)d_out, NBLK);
}